// Round 12
// baseline (475.147 us; speedup 1.0000x reference)
//
#include <hip/hip_runtime.h>

typedef __attribute__((ext_vector_type(8))) short bf16x8;
typedef __attribute__((ext_vector_type(16))) float f32x16;
typedef __attribute__((ext_vector_type(4))) float f32x4;
typedef __attribute__((ext_vector_type(4))) unsigned u32x4;

#define LN_EPS 1e-5f

__device__ __forceinline__ unsigned short f2bf(float f) {
    unsigned u = __float_as_uint(f);
    unsigned r = (u + 0x7FFFu + ((u >> 16) & 1u)) >> 16;
    return (unsigned short)r;
}

__device__ __forceinline__ unsigned cvt_pk_bf16(float lo, float hi) {
    unsigned r;
    asm("v_cvt_pk_bf16_f32 %0, %1, %2" : "=v"(r) : "v"(lo), "v"(hi));
    return r;
}

__device__ __forceinline__ void permswap(unsigned& a, unsigned& b) {
    asm("v_permlane32_swap_b32 %0, %1" : "+v"(a), "+v"(b));
}

// ---------------------------------------------------------------------------
// prep: build bf16 weight images in workspace (unchanged layout).
//   wimg [5][4][8][64][8] bf16: mats {W1a,W1b,W1c,W2,W3}^T in MFMA A-frag
//   order. ALL mats are now streamed from global (32 KB L1-hot phases).
// ---------------------------------------------------------------------------
__global__ void prep_weights(const float* __restrict__ W_lin,
                             const float* __restrict__ W1,
                             const float* __restrict__ W2,
                             const float* __restrict__ W3,
                             unsigned short* __restrict__ wt_lin,
                             unsigned short* __restrict__ wimg) {
    int i = blockIdx.x * blockDim.x + threadIdx.x;
    if (i < 128 * 256) {
        int n = i >> 8, k = i & 255;
        wt_lin[n * 256 + k] = f2bf(W_lin[k * 128 + n]);
    } else if (i < 128 * 256 + 5 * 16384) {
        int j = i - 128 * 256;
        int mat = j >> 14, r = j & 16383;
        int jj = r & 7, l = (r >> 3) & 63, ks = (r >> 9) & 7, f = r >> 12;
        int n = 32 * f + (l & 31);
        int k = 16 * ks + 8 * (l >> 5) + jj;
        float v;
        if (mat < 3)       v = W1[(mat * 128 + k) * 128 + n];
        else if (mat == 3) v = W2[k * 128 + n];
        else               v = W3[k * 128 + n];
        wimg[j] = f2bf(v);
    }
}

// ---------------------------------------------------------------------------
// atoms_gemm (unchanged)
// ---------------------------------------------------------------------------
__global__ void atoms_gemm(const float* __restrict__ af,
                           const unsigned short* __restrict__ wt_lin,
                           unsigned short* __restrict__ atoms_bf,
                           int Natoms) {
    const int wv = threadIdx.x >> 6, lane = threadIdx.x & 63;
    const int l31 = lane & 31, g8 = (lane >> 5) * 8, g4 = (lane >> 5) * 4;
    const int R = blockIdx.x * 128 + wv * 32;

    f32x16 acc[4];
#pragma unroll
    for (int f = 0; f < 4; ++f)
#pragma unroll
        for (int e = 0; e < 16; ++e) acc[f][e] = 0.0f;

    int arow = R + l31;
    if (arow >= Natoms) arow = Natoms - 1;
    const float* ap = af + (size_t)arow * 256;

#pragma unroll
    for (int ks = 0; ks < 16; ++ks) {
        const int k0 = ks * 16 + g8;
        float4 x0 = *(const float4*)(ap + k0);
        float4 x1 = *(const float4*)(ap + k0 + 4);
        bf16x8 a;
        a[0] = (short)f2bf(x0.x); a[1] = (short)f2bf(x0.y);
        a[2] = (short)f2bf(x0.z); a[3] = (short)f2bf(x0.w);
        a[4] = (short)f2bf(x1.x); a[5] = (short)f2bf(x1.y);
        a[6] = (short)f2bf(x1.z); a[7] = (short)f2bf(x1.w);
#pragma unroll
        for (int f = 0; f < 4; ++f) {
            bf16x8 b = *(const bf16x8*)(wt_lin + (32 * f + l31) * 256 + k0);
            acc[f] = __builtin_amdgcn_mfma_f32_32x32x16_bf16(a, b, acc[f], 0, 0, 0);
        }
    }

#pragma unroll
    for (int f = 0; f < 4; ++f) {
        const int col = 32 * f + l31;
#pragma unroll
        for (int r = 0; r < 16; ++r) {
            int row = R + (r & 3) + 8 * (r >> 2) + g4;
            if (row < Natoms) atoms_bf[(size_t)row * 128 + col] = f2bf(acc[f][r]);
        }
    }
}

// ---------------------------------------------------------------------------
// edge_fused R12: async-LDS gather prefetch, barrier-free.
// 512 thr / 8 waves, 2 tiles per wave (A, B). Per wave:
//  - B-tile dst rows prefetched via global_load_lds (per-lane gathered global
//    source -> wave-linear 8 KB LDS buffer) at kernel top: async, 0 VGPR,
//    cannot be sunk; in flight under all of tile A.
//  - A gathers -> regs (R9-proven, pinned); B src rows -> regs after A/chunk2
//    (reuses dying gs registers, +32 transient only).
//  - ALL 5 weight mats stream from global (32 KB L1-hot phases; no wlds, no
//    __syncthreads -> waves de-phase, no convoy).
//  - io (8 KB/wave): ef coalesced->bf16 bounce + residual + out bounce (R9).
// LDS: io 64 KB + gbufB 64 KB = 128 KB.
// ---------------------------------------------------------------------------
__global__ __launch_bounds__(512, 2) void edge_fused(
    const float* __restrict__ ef, const int* __restrict__ eidx,
    const unsigned short* __restrict__ atoms_bf,
    const unsigned short* __restrict__ wimg,
    const float* __restrict__ b1, const float* __restrict__ b2,
    const float* __restrict__ b3, const float* __restrict__ gamma_,
    const float* __restrict__ beta_, float* __restrict__ out, int E) {
    __shared__ unsigned short io[8][4096];    // 8 x 8 KB wave-private bounce
    __shared__ char gbufB[8][8192];           // 8 x 8 KB wave-private B-dst

    const int tid = threadIdx.x;
    const int lane = tid & 63, wv = tid >> 6;
    const int l31 = lane & 31, hi = lane >> 5, h8 = hi * 8;

    const int baseA = blockIdx.x * 512 + wv * 64;
    const int baseB = baseA + 32;
    const int eA = (baseA + l31) < E ? (baseA + l31) : E - 1;
    const int eB = (baseB + l31) < E ? (baseB + l31) : E - 1;

    // ---- tile A gathers -> regs, issued first (deepest latency) ----
    const int dIA = eidx[eA], sIA = eidx[E + eA];
    const unsigned short* dRowA = atoms_bf + (size_t)dIA * 128;
    const unsigned short* sRowA = atoms_bf + (size_t)sIA * 128;
    bf16x8 gd[8], gs[8];
#pragma unroll
    for (int ks = 0; ks < 8; ++ks) {
        gd[ks] = *(const bf16x8*)(dRowA + ks * 16 + h8);
        gs[ks] = *(const bf16x8*)(sRowA + ks * 16 + h8);
    }
#pragma unroll
    for (int ks = 0; ks < 8; ++ks)
        asm volatile("" :: "v"(gd[ks]), "v"(gs[ks]));  // pin: issue here

    // ---- tile B dst rows: async gather -> LDS (0 VGPR, can't be sunk) ----
    const int dIB = eidx[eB], sIB = eidx[E + eB];
    const unsigned short* dRowB = atoms_bf + (size_t)dIB * 128;
    const unsigned short* sRowB = atoms_bf + (size_t)sIB * 128;
    char* gb = &gbufB[wv][0];
#pragma unroll
    for (int ks = 0; ks < 8; ++ks)
        __builtin_amdgcn_global_load_lds(
            (const __attribute__((address_space(1))) unsigned int*)(dRowB + ks * 16 + h8),
            (__attribute__((address_space(3))) unsigned int*)(gb + ks * 1024 + lane * 16),
            16, 0, 0);

    // ---- ef(A): coalesced read -> bf16 -> swizzled wave-private io ----
    char* iow = (char*)&io[wv][0];
    const int r4 = lane >> 4;
    const int c8 = (lane & 15) * 8;
    auto fill_ef = [&](int base) {
#pragma unroll
        for (int i = 0; i < 8; ++i) {
            const int row = i * 4 + r4;
            int gr = base + row;
            if (gr >= E) gr = E - 1;
            const float* rp = ef + (size_t)gr * 128 + c8;
            f32x4 x0 = *(const f32x4*)(rp);
            f32x4 x1 = *(const f32x4*)(rp + 4);
            u32x4 w = (u32x4){cvt_pk_bf16(x0[0], x0[1]), cvt_pk_bf16(x0[2], x0[3]),
                              cvt_pk_bf16(x1[0], x1[1]), cvt_pk_bf16(x1[2], x1[3])};
            const int slot = (lane & 15) ^ (row & 7);
            *(u32x4*)(iow + row * 256 + slot * 16) = w;
        }
    };
    fill_ef(baseA);

    // weight mat bases (frag order; mat m at wimg + m*16384)
    const unsigned short* wg0 = wimg + 0 * 16384 + lane * 8;
    const unsigned short* wg1 = wimg + 1 * 16384 + lane * 8;
    const unsigned short* wg1c = wimg + 2 * 16384 + lane * 8;
    const unsigned short* wg2 = wimg + 3 * 16384 + lane * 8;
    const unsigned short* wg3 = wimg + 4 * 16384 + lane * 8;
    const int xr = l31 & 7;

    auto initb = [&](f32x16* acc, const float* __restrict__ bb) {
#pragma unroll
        for (int f = 0; f < 4; ++f)
#pragma unroll
            for (int m = 0; m < 4; ++m) {
                f32x4 b4 = *(const f32x4*)(bb + 32 * f + 8 * m + 4 * hi);
#pragma unroll
                for (int i = 0; i < 4; ++i) acc[f][4 * m + i] = b4[i];
            }
    };

    auto build_frags = [&](f32x16* acc, bf16x8* frag) {
#pragma unroll
        for (int f = 0; f < 4; ++f) {
            unsigned pk0[4], pk1[4];
#pragma unroll
            for (int m = 0; m < 4; ++m) {
                float a0 = fmaxf(acc[f][4 * m + 0], 0.0f);
                float a1 = fmaxf(acc[f][4 * m + 1], 0.0f);
                float a2 = fmaxf(acc[f][4 * m + 2], 0.0f);
                float a3 = fmaxf(acc[f][4 * m + 3], 0.0f);
                pk0[m] = cvt_pk_bf16(a0, a1);
                pk1[m] = cvt_pk_bf16(a2, a3);
            }
#pragma unroll
            for (int k1 = 0; k1 < 2; ++k1) {
                unsigned x0 = pk0[2 * k1], y0 = pk0[2 * k1 + 1];
                unsigned x1 = pk1[2 * k1], y1 = pk1[2 * k1 + 1];
                permswap(x0, y0);
                permswap(x1, y1);
                union { u32x4 u; bf16x8 b; } cv;
                cv.u = (u32x4){x0, x1, y0, y1};
                frag[2 * f + k1] = cv.b;
            }
        }
    };

    // chunks 1+2: W1a x dst-gather, W1b x src-gather (both from regs)
    auto l1_gathers = [&](f32x16* acc, const bf16x8* gdv, const bf16x8* gsv) {
#pragma unroll
        for (int ks = 0; ks < 8; ++ks)
#pragma unroll
            for (int f = 0; f < 4; ++f) {
                bf16x8 a = *(const bf16x8*)(wg0 + (f * 8 + ks) * 512);
                acc[f] = __builtin_amdgcn_mfma_f32_32x32x16_bf16(a, gdv[ks], acc[f], 0, 0, 0);
            }
#pragma unroll
        for (int ks = 0; ks < 8; ++ks)
#pragma unroll
            for (int f = 0; f < 4; ++f) {
                bf16x8 a = *(const bf16x8*)(wg1 + (f * 8 + ks) * 512);
                acc[f] = __builtin_amdgcn_mfma_f32_32x32x16_bf16(a, gsv[ks], acc[f], 0, 0, 0);
            }
    };

    // chunk 3 (ef from io) + layer 2 + layer 3
    auto c3_l2_l3 = [&](f32x16* acc, bf16x8* frag) {
#pragma unroll
        for (int ks = 0; ks < 8; ++ks) {
            const int slot = (2 * ks + hi) ^ xr;
            bf16x8 bx = *(const bf16x8*)(iow + l31 * 256 + slot * 16);
#pragma unroll
            for (int f = 0; f < 4; ++f) {
                bf16x8 a = *(const bf16x8*)(wg1c + (f * 8 + ks) * 512);
                acc[f] = __builtin_amdgcn_mfma_f32_32x32x16_bf16(a, bx, acc[f], 0, 0, 0);
            }
        }
        build_frags(acc, frag);
        initb(acc, b2);
        // NOTE: frag holds layer-1 output; acc re-initialized to b2 AFTER
        // build_frags consumed it.
#pragma unroll
        for (int ks = 0; ks < 8; ++ks)
#pragma unroll
            for (int f = 0; f < 4; ++f) {
                bf16x8 a = *(const bf16x8*)(wg2 + (f * 8 + ks) * 512);
                acc[f] = __builtin_amdgcn_mfma_f32_32x32x16_bf16(a, frag[ks], acc[f], 0, 0, 0);
            }
        build_frags(acc, frag);
        initb(acc, b3);
#pragma unroll
        for (int ks = 0; ks < 8; ++ks)
#pragma unroll
            for (int f = 0; f < 4; ++f) {
                bf16x8 a = *(const bf16x8*)(wg3 + (f * 8 + ks) * 512);
                acc[f] = __builtin_amdgcn_mfma_f32_32x32x16_bf16(a, frag[ks], acc[f], 0, 0, 0);
            }
    };

    auto epilogue = [&](f32x16* acc, int base) {
        float s = 0.0f, q = 0.0f;
#pragma unroll
        for (int f = 0; f < 4; ++f)
#pragma unroll
            for (int m = 0; m < 4; ++m) {
                const int slot = (4 * f + m) ^ xr;
                uint2 w = *(const uint2*)(iow + l31 * 256 + slot * 16 + 8 * hi);
                float r0 = __uint_as_float(w.x << 16);
                float r1 = __uint_as_float(w.x & 0xffff0000u);
                float r2 = __uint_as_float(w.y << 16);
                float r3 = __uint_as_float(w.y & 0xffff0000u);
                float v0 = acc[f][4 * m + 0] + r0;
                float v1 = acc[f][4 * m + 1] + r1;
                float v2 = acc[f][4 * m + 2] + r2;
                float v3 = acc[f][4 * m + 3] + r3;
                acc[f][4 * m + 0] = v0; acc[f][4 * m + 1] = v1;
                acc[f][4 * m + 2] = v2; acc[f][4 * m + 3] = v3;
                s += v0 + v1 + v2 + v3;
                q += v0 * v0 + v1 * v1 + v2 * v2 + v3 * v3;
            }
        s += __shfl_xor(s, 32, 64);
        q += __shfl_xor(q, 32, 64);
        const float mu = s * (1.0f / 128.0f);
        const float var = q * (1.0f / 128.0f) - mu * mu;
        const float rs = rsqrtf(var + LN_EPS);

#pragma unroll
        for (int h = 0; h < 2; ++h) {
#pragma unroll
            for (int f2 = 0; f2 < 2; ++f2) {
                const int f = 2 * h + f2;
#pragma unroll
                for (int m = 0; m < 4; ++m) {
                    f32x4 g4 = *(const f32x4*)(gamma_ + 32 * f + 8 * m + 4 * hi);
                    f32x4 be4 = *(const f32x4*)(beta_ + 32 * f + 8 * m + 4 * hi);
                    f32x4 o;
#pragma unroll
                    for (int i = 0; i < 4; ++i)
                        o[i] = (acc[f][4 * m + i] - mu) * rs * g4[i] + be4[i];
                    const int slot = (8 * f2 + 2 * m + hi) ^ xr;
                    *(f32x4*)(iow + l31 * 256 + slot * 16) = o;
                }
            }
#pragma unroll
            for (int i = 0; i < 8; ++i) {
                const int row = i * 4 + r4;
                const int slot = (lane & 15) ^ (row & 7);
                f32x4 v = *(const f32x4*)(iow + row * 256 + slot * 16);
                const int edge = base + row;
                if (edge < E)
                    *(f32x4*)(out + (size_t)edge * 128 + h * 64 + (lane & 15) * 4) = v;
            }
        }
    };

    f32x16 acc[4];
    bf16x8 frag[8];

    // =================== tile A ===================
    initb(acc, b1);
    l1_gathers(acc, gd, gs);

    // gs now dead: issue B's src gathers into fresh regs (one set, pinned)
    bf16x8 gsB[8];
#pragma unroll
    for (int ks = 0; ks < 8; ++ks)
        gsB[ks] = *(const bf16x8*)(sRowB + ks * 16 + h8);
#pragma unroll
    for (int ks = 0; ks < 8; ++ks)
        asm volatile("" :: "v"(gsB[ks]));

    c3_l2_l3(acc, frag);
    epilogue(acc, baseA);

    // =================== tile B ===================
    // B-dst prefetch landed long ago; wait drains it (and A's stores).
    asm volatile("s_waitcnt vmcnt(0)" ::: "memory");
    fill_ef(baseB);  // io free after A's epilogue (program order, wave-local)
#pragma unroll
    for (int ks = 0; ks < 8; ++ks)
        gd[ks] = *(const bf16x8*)(gb + ks * 1024 + lane * 16);

    initb(acc, b1);
    l1_gathers(acc, gd, gsB);
    c3_l2_l3(acc, frag);
    epilogue(acc, baseB);
}

// ---------------------------------------------------------------------------
extern "C" void kernel_launch(void* const* d_in, const int* in_sizes, int n_in,
                              void* d_out, int out_size, void* d_ws, size_t ws_size,
                              hipStream_t stream) {
    const float* atom_features = (const float*)d_in[0];
    const float* edge_features = (const float*)d_in[1];
    const int* edge_index = (const int*)d_in[2];
    const float* W_lin = (const float*)d_in[3];
    const float* W1 = (const float*)d_in[4];
    const float* b1 = (const float*)d_in[5];
    const float* W2 = (const float*)d_in[6];
    const float* b2 = (const float*)d_in[7];
    const float* W3 = (const float*)d_in[8];
    const float* b3 = (const float*)d_in[9];
    const float* gamma_ = (const float*)d_in[10];
    const float* beta_ = (const float*)d_in[11];
    float* out = (float*)d_out;

    const int Natoms = in_sizes[0] / 256;
    const int E = in_sizes[1] / 128;

    unsigned short* atoms_bf = (unsigned short*)d_ws;
    unsigned short* wt_lin = atoms_bf + (size_t)Natoms * 128;
    unsigned short* wimg = wt_lin + 128 * 256;

    const int prep_items = 128 * 256 + 5 * 16384;
    prep_weights<<<(prep_items + 255) / 256, 256, 0, stream>>>(W_lin, W1, W2, W3,
                                                               wt_lin, wimg);
    atoms_gemm<<<(Natoms + 127) / 128, 256, 0, stream>>>(atom_features, wt_lin,
                                                         atoms_bf, Natoms);
    edge_fused<<<(E + 511) / 512, 512, 0, stream>>>(edge_features, edge_index,
                                                    atoms_bf, wimg, b1, b2, b3,
                                                    gamma_, beta_, out, E);
}

// Round 15
// 252.796 us; speedup vs baseline: 1.8796x; 1.8796x over previous
//
#include <hip/hip_runtime.h>

typedef __attribute__((ext_vector_type(8))) short bf16x8;
typedef __attribute__((ext_vector_type(16))) float f32x16;
typedef __attribute__((ext_vector_type(4))) float f32x4;
typedef __attribute__((ext_vector_type(4))) unsigned u32x4;

#define LN_EPS 1e-5f

__device__ __forceinline__ unsigned short f2bf(float f) {
    unsigned u = __float_as_uint(f);
    unsigned r = (u + 0x7FFFu + ((u >> 16) & 1u)) >> 16;
    return (unsigned short)r;
}

__device__ __forceinline__ unsigned cvt_pk_bf16(float lo, float hi) {
    unsigned r;
    asm("v_cvt_pk_bf16_f32 %0, %1, %2" : "=v"(r) : "v"(lo), "v"(hi));
    return r;
}

__device__ __forceinline__ void permswap(unsigned& a, unsigned& b) {
    asm("v_permlane32_swap_b32 %0, %1" : "+v"(a), "+v"(b));
}

// ---------------------------------------------------------------------------
// prep: build bf16 weight images in workspace (R9 layout).
//   wt_lin [128][256]            = W_lin^T  (B-operand image for atoms_gemm)
//   wimg   [5][4][8][64][8] bf16 = {W1a,W1b,W1c,W2,W3}^T in MFMA A-frag order
//   mats 0,1 staged to LDS by edge_fused; mats 2,3,4 L1-hot global streams.
// ---------------------------------------------------------------------------
__global__ void prep_weights(const float* __restrict__ W_lin,
                             const float* __restrict__ W1,
                             const float* __restrict__ W2,
                             const float* __restrict__ W3,
                             unsigned short* __restrict__ wt_lin,
                             unsigned short* __restrict__ wimg) {
    int i = blockIdx.x * blockDim.x + threadIdx.x;
    if (i < 128 * 256) {
        int n = i >> 8, k = i & 255;
        wt_lin[n * 256 + k] = f2bf(W_lin[k * 128 + n]);
    } else if (i < 128 * 256 + 5 * 16384) {
        int j = i - 128 * 256;
        int mat = j >> 14, r = j & 16383;
        int jj = r & 7, l = (r >> 3) & 63, ks = (r >> 9) & 7, f = r >> 12;
        int n = 32 * f + (l & 31);
        int k = 16 * ks + 8 * (l >> 5) + jj;
        float v;
        if (mat < 3)       v = W1[(mat * 128 + k) * 128 + n];
        else if (mat == 3) v = W2[k * 128 + n];
        else               v = W3[k * 128 + n];
        wimg[j] = f2bf(v);
    }
}

// ---------------------------------------------------------------------------
// atoms_gemm: atom_scalars(bf16)[N][128] = atom_features[N][256] @ W_lin
// ---------------------------------------------------------------------------
__global__ void atoms_gemm(const float* __restrict__ af,
                           const unsigned short* __restrict__ wt_lin,
                           unsigned short* __restrict__ atoms_bf,
                           int Natoms) {
    const int wv = threadIdx.x >> 6, lane = threadIdx.x & 63;
    const int l31 = lane & 31, g8 = (lane >> 5) * 8, g4 = (lane >> 5) * 4;
    const int R = blockIdx.x * 128 + wv * 32;

    f32x16 acc[4];
#pragma unroll
    for (int f = 0; f < 4; ++f)
#pragma unroll
        for (int e = 0; e < 16; ++e) acc[f][e] = 0.0f;

    int arow = R + l31;
    if (arow >= Natoms) arow = Natoms - 1;
    const float* ap = af + (size_t)arow * 256;

#pragma unroll
    for (int ks = 0; ks < 16; ++ks) {
        const int k0 = ks * 16 + g8;
        float4 x0 = *(const float4*)(ap + k0);
        float4 x1 = *(const float4*)(ap + k0 + 4);
        bf16x8 a;
        a[0] = (short)f2bf(x0.x); a[1] = (short)f2bf(x0.y);
        a[2] = (short)f2bf(x0.z); a[3] = (short)f2bf(x0.w);
        a[4] = (short)f2bf(x1.x); a[5] = (short)f2bf(x1.y);
        a[6] = (short)f2bf(x1.z); a[7] = (short)f2bf(x1.w);
#pragma unroll
        for (int f = 0; f < 4; ++f) {
            bf16x8 b = *(const bf16x8*)(wt_lin + (32 * f + l31) * 256 + k0);
            acc[f] = __builtin_amdgcn_mfma_f32_32x32x16_bf16(a, b, acc[f], 0, 0, 0);
        }
    }

#pragma unroll
    for (int f = 0; f < 4; ++f) {
        const int col = 32 * f + l31;
#pragma unroll
        for (int r = 0; r < 16; ++r) {
            int row = R + (r & 3) + 8 * (r >> 2) + g4;
            if (row < Natoms) atoms_bf[(size_t)row * 128 + col] = f2bf(acc[f][r]);
        }
    }
}

// ---------------------------------------------------------------------------
// edge_fused (R9, verified 254.6 us): coalesced-everything except gathers.
// 512 thr / 8 waves, 32 edges per wave, 256 edges per block.
// LDS: W1a+W1b (64 KB) + 8 x 8 KB wave-private io buffers.
// ef: coalesced global read -> bf16 -> swizzled LDS; chunk-3 frags and the
// residual come from LDS. out: epilogue -> LDS -> coalesced global stores.
// W1c/W2/W3 stream from global (L1-hot phases). Gathers issue pre-barrier.
// ---------------------------------------------------------------------------
__global__ __launch_bounds__(512, 2) void edge_fused(
    const float* __restrict__ ef, const int* __restrict__ eidx,
    const unsigned short* __restrict__ atoms_bf,
    const unsigned short* __restrict__ wimg,
    const float* __restrict__ b1, const float* __restrict__ b2,
    const float* __restrict__ b3, const float* __restrict__ gamma_,
    const float* __restrict__ beta_, float* __restrict__ out, int E) {
    __shared__ unsigned short wlds[2 * 16384];  // 64 KB: W1a, W1b
    __shared__ unsigned short io[8][4096];      // 8 x 8 KB wave-private

    const int tid = threadIdx.x;
    const int lane = tid & 63, wv = tid >> 6;
    const int l31 = lane & 31, hi = lane >> 5, h8 = hi * 8;

    // ---- (1) stage W1a+W1b: 512 thr x 16 B x 8 iters (linear) ----
    {
        const char* s = (const char*)wimg;
        char* d = (char*)wlds;
        const int o = tid * 16;
#pragma unroll
        for (int i = 0; i < 8; ++i)
            __builtin_amdgcn_global_load_lds(
                (const __attribute__((address_space(1))) unsigned int*)(s + o + i * 8192),
                (__attribute__((address_space(3))) unsigned int*)(d + o + i * 8192),
                16, 0, 0);
    }

    const int edgeBase = blockIdx.x * 256 + wv * 32;
    const int e0 = edgeBase + l31;
    const int e = e0 < E ? e0 : E - 1;

    // ---- (2) issue gathers (kept live across the barrier) ----
    const int dI = eidx[e], sI = eidx[E + e];
    const unsigned short* dRow = atoms_bf + (size_t)dI * 128;
    const unsigned short* sRow = atoms_bf + (size_t)sI * 128;
    bf16x8 gd[8], gs[8];
#pragma unroll
    for (int ks = 0; ks < 8; ++ks) {
        gd[ks] = *(const bf16x8*)(dRow + ks * 16 + h8);
        gs[ks] = *(const bf16x8*)(sRow + ks * 16 + h8);
    }

    // ---- (3) ef coalesced read -> bf16 -> swizzled wave-private LDS ----
    char* iow = (char*)&io[wv][0];
    {
        const int r4 = lane >> 4;        // row sub-index 0..3
        const int c8 = (lane & 15) * 8;  // float offset within row
#pragma unroll
        for (int i = 0; i < 8; ++i) {
            const int row = i * 4 + r4;  // 0..31 (wave-local edge)
            int gr = edgeBase + row;
            if (gr >= E) gr = E - 1;
            const float* rp = ef + (size_t)gr * 128 + c8;
            f32x4 x0 = *(const f32x4*)(rp);
            f32x4 x1 = *(const f32x4*)(rp + 4);
            u32x4 w = (u32x4){cvt_pk_bf16(x0[0], x0[1]), cvt_pk_bf16(x0[2], x0[3]),
                              cvt_pk_bf16(x1[0], x1[1]), cvt_pk_bf16(x1[2], x1[3])};
            const int slot = (lane & 15) ^ (row & 7);
            *(u32x4*)(iow + row * 256 + slot * 16) = w;
        }
    }

    // keep gathers alive (prevent sinking past the barrier)
#pragma unroll
    for (int ks = 0; ks < 8; ++ks)
        asm volatile("" :: "v"(gd[ks]), "v"(gs[ks]));

    f32x16 acc[4];
    auto initb = [&](const float* __restrict__ bb) {
#pragma unroll
        for (int f = 0; f < 4; ++f)
#pragma unroll
            for (int m = 0; m < 4; ++m) {
                f32x4 b4 = *(const f32x4*)(bb + 32 * f + 8 * m + 4 * hi);
#pragma unroll
                for (int i = 0; i < 4; ++i) acc[f][4 * m + i] = b4[i];
            }
    };

    bf16x8 frag[8];
    auto build_frags = [&]() {
#pragma unroll
        for (int f = 0; f < 4; ++f) {
            unsigned pk0[4], pk1[4];
#pragma unroll
            for (int m = 0; m < 4; ++m) {
                float a0 = fmaxf(acc[f][4 * m + 0], 0.0f);
                float a1 = fmaxf(acc[f][4 * m + 1], 0.0f);
                float a2 = fmaxf(acc[f][4 * m + 2], 0.0f);
                float a3 = fmaxf(acc[f][4 * m + 3], 0.0f);
                pk0[m] = cvt_pk_bf16(a0, a1);
                pk1[m] = cvt_pk_bf16(a2, a3);
            }
#pragma unroll
            for (int k1 = 0; k1 < 2; ++k1) {
                unsigned x0 = pk0[2 * k1], y0 = pk0[2 * k1 + 1];
                unsigned x1 = pk1[2 * k1], y1 = pk1[2 * k1 + 1];
                permswap(x0, y0);
                permswap(x1, y1);
                union { u32x4 u; bf16x8 b; } cv;
                cv.u = (u32x4){x0, x1, y0, y1};
                frag[2 * f + k1] = cv.b;
            }
        }
    };

    const unsigned short* lbase = wlds + lane * 8;  // + ((mat*4+f)*8+ks)*512
    const unsigned short* wg1c = wimg + 2 * 16384 + lane * 8;
    const unsigned short* wg2 = wimg + 3 * 16384 + lane * 8;
    const unsigned short* wg3 = wimg + 4 * 16384 + lane * 8;
    const int xr = l31 & 7;  // io swizzle key for this lane's edge-row

    __syncthreads();

    // ---------------- layer 1, chunk 1: W1a (LDS) x dst gathers ----------
    initb(b1);
#pragma unroll
    for (int ks = 0; ks < 8; ++ks)
#pragma unroll
        for (int f = 0; f < 4; ++f) {
            bf16x8 a = *(const bf16x8*)(lbase + ((0 * 4 + f) * 8 + ks) * 512);
            acc[f] = __builtin_amdgcn_mfma_f32_32x32x16_bf16(a, gd[ks], acc[f], 0, 0, 0);
        }
    // ---------------- chunk 2: W1b (LDS) x src gathers ----------
#pragma unroll
    for (int ks = 0; ks < 8; ++ks)
#pragma unroll
        for (int f = 0; f < 4; ++f) {
            bf16x8 a = *(const bf16x8*)(lbase + ((1 * 4 + f) * 8 + ks) * 512);
            acc[f] = __builtin_amdgcn_mfma_f32_32x32x16_bf16(a, gs[ks], acc[f], 0, 0, 0);
        }
    // ---------------- chunk 3: W1c (global, L1-hot) x ef frags (LDS) -----
#pragma unroll
    for (int ks = 0; ks < 8; ++ks) {
        const int slot = (2 * ks + hi) ^ xr;
        bf16x8 bx = *(const bf16x8*)(iow + l31 * 256 + slot * 16);
#pragma unroll
        for (int f = 0; f < 4; ++f) {
            bf16x8 a = *(const bf16x8*)(wg1c + (f * 8 + ks) * 512);
            acc[f] = __builtin_amdgcn_mfma_f32_32x32x16_bf16(a, bx, acc[f], 0, 0, 0);
        }
    }

    // ---------------- layer 2: W2 (global, L1-hot) ----------------
    build_frags();
    initb(b2);
#pragma unroll
    for (int ks = 0; ks < 8; ++ks)
#pragma unroll
        for (int f = 0; f < 4; ++f) {
            bf16x8 a = *(const bf16x8*)(wg2 + (f * 8 + ks) * 512);
            acc[f] = __builtin_amdgcn_mfma_f32_32x32x16_bf16(a, frag[ks], acc[f], 0, 0, 0);
        }

    // ---------------- layer 3: W3 (global, L1-hot) ----------------
    build_frags();
    initb(b3);
#pragma unroll
    for (int ks = 0; ks < 8; ++ks)
#pragma unroll
        for (int f = 0; f < 4; ++f) {
            bf16x8 a = *(const bf16x8*)(wg3 + (f * 8 + ks) * 512);
            acc[f] = __builtin_amdgcn_mfma_f32_32x32x16_bf16(a, frag[ks], acc[f], 0, 0, 0);
        }

    // ---------------- residual (LDS) + LayerNorm ----------------
    float s = 0.0f, q = 0.0f;
#pragma unroll
    for (int f = 0; f < 4; ++f)
#pragma unroll
        for (int m = 0; m < 4; ++m) {
            const int slot = (4 * f + m) ^ xr;
            uint2 w = *(const uint2*)(iow + l31 * 256 + slot * 16 + 8 * hi);
            float r0 = __uint_as_float(w.x << 16);
            float r1 = __uint_as_float(w.x & 0xffff0000u);
            float r2 = __uint_as_float(w.y << 16);
            float r3 = __uint_as_float(w.y & 0xffff0000u);
            float v0 = acc[f][4 * m + 0] + r0;
            float v1 = acc[f][4 * m + 1] + r1;
            float v2 = acc[f][4 * m + 2] + r2;
            float v3 = acc[f][4 * m + 3] + r3;
            acc[f][4 * m + 0] = v0; acc[f][4 * m + 1] = v1;
            acc[f][4 * m + 2] = v2; acc[f][4 * m + 3] = v3;
            s += v0 + v1 + v2 + v3;
            q += v0 * v0 + v1 * v1 + v2 * v2 + v3 * v3;
        }
    s += __shfl_xor(s, 32, 64);
    q += __shfl_xor(q, 32, 64);
    const float mu = s * (1.0f / 128.0f);
    const float var = q * (1.0f / 128.0f) - mu * mu;
    const float rs = rsqrtf(var + LN_EPS);

    // ---------------- out: LDS bounce -> coalesced stores (2 halves) ------
#pragma unroll
    for (int h = 0; h < 2; ++h) {
        // normalize + write this half into the wave buffer (f32)
#pragma unroll
        for (int f2 = 0; f2 < 2; ++f2) {
            const int f = 2 * h + f2;
#pragma unroll
            for (int m = 0; m < 4; ++m) {
                f32x4 g4 = *(const f32x4*)(gamma_ + 32 * f + 8 * m + 4 * hi);
                f32x4 be4 = *(const f32x4*)(beta_ + 32 * f + 8 * m + 4 * hi);
                f32x4 o;
#pragma unroll
                for (int i = 0; i < 4; ++i)
                    o[i] = (acc[f][4 * m + i] - mu) * rs * g4[i] + be4[i];
                const int slot = (8 * f2 + 2 * m + hi) ^ xr;
                *(f32x4*)(iow + l31 * 256 + slot * 16) = o;
            }
        }
        // coalesced read-back + global store: 8 iters x 4 rows = all 32 rows
        const int r4 = lane >> 4;
#pragma unroll
        for (int i = 0; i < 8; ++i) {
            const int row = i * 4 + r4;
            const int slot = (lane & 15) ^ (row & 7);
            f32x4 v = *(const f32x4*)(iow + row * 256 + slot * 16);
            const int edge = edgeBase + row;
            if (edge < E)
                *(f32x4*)(out + (size_t)edge * 128 + h * 64 + (lane & 15) * 4) = v;
        }
    }
}

// ---------------------------------------------------------------------------
extern "C" void kernel_launch(void* const* d_in, const int* in_sizes, int n_in,
                              void* d_out, int out_size, void* d_ws, size_t ws_size,
                              hipStream_t stream) {
    const float* atom_features = (const float*)d_in[0];
    const float* edge_features = (const float*)d_in[1];
    const int* edge_index = (const int*)d_in[2];
    const float* W_lin = (const float*)d_in[3];
    const float* W1 = (const float*)d_in[4];
    const float* b1 = (const float*)d_in[5];
    const float* W2 = (const float*)d_in[6];
    const float* b2 = (const float*)d_in[7];
    const float* W3 = (const float*)d_in[8];
    const float* b3 = (const float*)d_in[9];
    const float* gamma_ = (const float*)d_in[10];
    const float* beta_ = (const float*)d_in[11];
    float* out = (float*)d_out;

    const int Natoms = in_sizes[0] / 256;
    const int E = in_sizes[1] / 128;

    unsigned short* atoms_bf = (unsigned short*)d_ws;
    unsigned short* wt_lin = atoms_bf + (size_t)Natoms * 128;
    unsigned short* wimg = wt_lin + 128 * 256;

    const int prep_items = 128 * 256 + 5 * 16384;
    prep_weights<<<(prep_items + 255) / 256, 256, 0, stream>>>(W_lin, W1, W2, W3,
                                                               wt_lin, wimg);
    atoms_gemm<<<(Natoms + 127) / 128, 256, 0, stream>>>(atom_features, wt_lin,
                                                         atoms_bf, Natoms);
    edge_fused<<<(E + 255) / 256, 512, 0, stream>>>(edge_features, edge_index,
                                                    atoms_bf, wimg, b1, b2, b3,
                                                    gamma_, beta_, out, E);
}